// Round 13
// baseline (386.744 us; speedup 1.0000x reference)
//
#include <hip/hip_runtime.h>
#include <hip/hip_bf16.h>

typedef __hip_bfloat16 bf16;
typedef __attribute__((ext_vector_type(8))) short short8;   // 8 bf16 (4 VGPRs)
typedef __attribute__((ext_vector_type(4))) float f32x4;    // 4 fp32 acc
typedef __attribute__((ext_vector_type(2))) float f32x2;
typedef _Float16 h2 __attribute__((ext_vector_type(2)));    // packed half2

constexpr int NN = 50000;   // nodes
constexpr int NE = 800000;  // edges
constexpr int IC = 64;      // in channels
constexpr int OC = 128;     // out channels
constexpr int NH = 4;       // heads
constexpr unsigned F32_ONE = 0x3F800000u;
// 1/sqrt(32) * log2(e): exp(l) = exp2(l*log2e), constants fused
constexpr float KC = 0.25503486f;

__device__ __forceinline__ float ldf(const void* p, int i, bool f32) {
    return f32 ? ((const float*)p)[i]
               : __bfloat162float(((const bf16*)p)[i]);
}

__device__ __forceinline__ int ld_idx(const void* p, long long i, bool i64) {
    return i64 ? (int)((const long long*)p)[i] : ((const int*)p)[i];
}

__device__ __forceinline__ bool probe_i64(const void* ei) {
    const unsigned* u = (const unsigned*)ei;
    return (u[1] | u[3] | u[5] | u[7]) == 0u;
}

// f32 -> bf16 bits (RNE)
__device__ __forceinline__ unsigned f2bu(float x) {
    unsigned u = __float_as_uint(x);
    return (u + 0x7FFFu + ((u >> 16) & 1u)) >> 16;
}

__device__ __forceinline__ h2 u2h(unsigned u) { return __builtin_bit_cast(h2, u); }

// dot2: c += a[0]*b[0] + a[1]*b[1] (f16 inputs, f32 accum)
__device__ __forceinline__ float fdot2(h2 a, h2 b, float c) {
#if __has_builtin(__builtin_amdgcn_fdot2)
    return __builtin_amdgcn_fdot2(a, b, c, false);
#else
    return c + (float)a[0] * (float)b[0] + (float)a[1] * (float)b[1];
#endif
}

__device__ __forceinline__ h2 relu2(h2 a) {
    h2 z = {(_Float16)0.f, (_Float16)0.f};
#if __has_builtin(__builtin_elementwise_max)
    return __builtin_elementwise_max(a, z);
#else
    h2 r;
    r[0] = a[0] > (_Float16)0.f ? a[0] : (_Float16)0.f;
    r[1] = a[1] > (_Float16)0.f ? a[1] : (_Float16)0.f;
    return r;
#endif
}

// Single-instruction DPP add: x = dpp(x) + x (VOP2 DPP encoding).
// ctrl strings: xor1 = quad_perm:[1,0,3,2], xor2 = quad_perm:[2,3,0,1],
// xor8-in-row = row_ror:8, xor4-in-row = row_ror:4 (full 16-lane allreduce).
#define DPPFADD(x, ctrl) \
    asm("v_add_f32 %0, %0, %0 " ctrl " row_mask:0xf bank_mask:0xf" : "+v"(x))

// wave-uniform value -> SGPR (compiler can't prove threadIdx.x>>6 uniform)
__device__ __forceinline__ int rfl(int v) { return __builtin_amdgcn_readfirstlane(v); }

// x-row fragment load: bf16 input -> direct short8; f32 input -> float4 pair
// + one-time RNE convert (same rounding as __float2bfloat16).
__device__ __forceinline__ short8 ld_xrow(const void* x, bool f32, int m, int off) {
    if (!f32) return *(const short8*)((const bf16*)x + (size_t)m * IC + off);
    const float* xr = (const float*)x + (size_t)m * IC + off;
    float4 u0 = *(const float4*)xr;
    float4 u1 = *(const float4*)(xr + 4);
    short8 r;
    r[0] = (short)f2bu(u0.x); r[1] = (short)f2bu(u0.y);
    r[2] = (short)f2bu(u0.z); r[3] = (short)f2bu(u0.w);
    r[4] = (short)f2bu(u1.x); r[5] = (short)f2bu(u1.y);
    r[6] = (short)f2bu(u1.z); r[7] = (short)f2bu(u1.w);
    return r;
}

// ---- fp8 e4m3 helpers ------------------------------------------------------
__device__ __forceinline__ unsigned char f32_to_fp8(float x) {
#if __has_builtin(__builtin_amdgcn_cvt_pk_fp8_f32)
    return (unsigned char)(__builtin_amdgcn_cvt_pk_fp8_f32(x, x, 0, false) & 0xFF);
#else
    unsigned bits = __float_as_uint(x);
    unsigned s = bits >> 31;
    float a = fabsf(x);
    if (a >= 448.f) return (unsigned char)((s << 7) | 0x7E);
    if (a < 0.015625f) {
        int m = (int)(a * 512.f + 0.5f);
        if (m >= 8) return (unsigned char)((s << 7) | 0x08);
        return (unsigned char)((s << 7) | m);
    }
    unsigned ab = (bits & 0x7FFFFFFFu) + 0x00080000u;
    int e8 = (int)(ab >> 23) - 127 + 7;
    unsigned m3 = (ab >> 20) & 7u;
    if (e8 >= 16) return (unsigned char)((s << 7) | 0x7E);
    return (unsigned char)((s << 7) | ((unsigned)e8 << 3) | m3);
#endif
}

__device__ __forceinline__ void fp8x2_to_f32(unsigned u, float& f0, float& f1) {
#if __has_builtin(__builtin_amdgcn_cvt_pk_f32_fp8)
    f32x2 lo = __builtin_amdgcn_cvt_pk_f32_fp8(u, false);
    f0 = lo[0]; f1 = lo[1];
#else
    float r[2];
#pragma unroll
    for (int j = 0; j < 2; ++j) {
        unsigned b = (u >> (8 * j)) & 0xFF;
        unsigned s = b >> 7, e = (b >> 3) & 15, m = b & 7;
        float v = (e == 0) ? (float)m * 0.001953125f
                           : __uint_as_float(((e + 120u) << 23) | (m << 20));
        r[j] = s ? -v : v;
    }
    f0 = r[0]; f1 = r[1];
#endif
}

// ---------------------------------------------------------------------------
// prep: weight conversions + csr_count. (cnt/ssum zeroed by memset)
// Counting atomicAdd's return value = edge's rank within dst bucket -> rank[e];
// csr_fill then needs NO atomics: pos = rowptr[d] + rank[e].
// bcat: [0,128)=bq, [128,256)=bk, [256,384)=bv, [384,512)=0 (a), [512,640)=be1 (b')
// We2h packing (edge_gather 16-lane scheme, R4 layout): entry t = lane*4 + k,
//   lane: g = lane>>4 (head), i = lane&15; pair index pp = 4*i + k;
//   value = half2( We2[2pp][g], We2[2pp+1][g] ).
// ---------------------------------------------------------------------------
constexpr int PB_W   = 160;
constexpr int PB_WO  = 64;
constexpr int PB_CNT = 3125;   // csr_count: NE/256

__global__ __launch_bounds__(256) void prep(
    const void* __restrict__ Wq, const void* __restrict__ bq,
    const void* __restrict__ Wk, const void* __restrict__ bk,
    const void* __restrict__ Wv, const void* __restrict__ bv,
    const void* __restrict__ We1, const void* __restrict__ be1,
    const void* __restrict__ We2, const void* __restrict__ be2,
    const void* __restrict__ Wo,  const unsigned* __restrict__ gw,
    const void* __restrict__ eia, const void* __restrict__ eib, int split,
    bf16* __restrict__ WcatT, bf16* __restrict__ WoT,
    int* __restrict__ cnt, int* __restrict__ rank,
    unsigned* __restrict__ We2h, float* __restrict__ be2f,
    float* __restrict__ bcat)
{
    const bool f32 = (gw[0] == F32_ONE);
    int b = blockIdx.x, t = threadIdx.x;
    if (b < PB_W) {
        int idx = b * 256 + t;                  // n*64 + k
        int n = idx >> 6, k = idx & 63;
        int sel = n >> 7, c = n & 127;
        float v;
        if (sel == 0)      v = ldf(Wq, k * OC + c, f32);
        else if (sel == 1) v = ldf(Wk, k * OC + c, f32);
        else if (sel == 2) v = ldf(Wv, k * OC + c, f32);
        else if (sel == 3) v = ldf(We1, k * OC + c, f32);
        else               v = ldf(We1, (IC + k) * OC + c, f32);
        WcatT[idx] = __float2bfloat16(v);
    } else if (b < PB_W + PB_WO) {
        int idx = (b - PB_W) * 256 + t;         // n*128 + k
        int n = idx >> 7, k = idx & 127;
        WoT[idx] = __float2bfloat16(ldf(Wo, k * OC + n, f32));
    } else if (b < PB_W + PB_WO + PB_CNT) {
        const bool i64 = probe_i64(eia);
        long long e = (long long)(b - PB_W - PB_WO) * 256 + t;
        int d = split ? ld_idx(eib, e, i64) : ld_idx(eia, NE + e, i64);
        int r = atomicAdd(&cnt[d], 1);
        rank[e] = r;
    } else {
        if (t < NH) be2f[t] = ldf(be2, t, f32);
        // We2h: 64 lanes x 4 dwords, per-lane 8-channel weight slice for ONE head
        {
            int ln = t >> 2, k = t & 3;         // t in [0,256)
            int g = ln >> 4, ii = ln & 15;
            int pp = 4 * ii + k;
            h2 hv;
            hv[0] = (_Float16)ldf(We2, (2 * pp) * NH + g, f32);
            hv[1] = (_Float16)ldf(We2, (2 * pp + 1) * NH + g, f32);
            We2h[t] = __builtin_bit_cast(unsigned, hv);
        }
        for (int n = t; n < 5 * OC; n += 256) {
            int sel = n >> 7, c = n & 127;
            float bb = 0.f;
            if (sel == 0) bb = ldf(bq, c, f32);
            else if (sel == 1) bb = ldf(bk, c, f32);
            else if (sel == 2) bb = ldf(bv, c, f32);
            else if (sel == 4) bb = ldf(be1, c, f32);  // fold be1 into b'
            bcat[n] = bb;
        }
    }
}

// ---------------------------------------------------------------------------
// Parallel CSR scan:
//   scan_part: 49 blocks x 1024 elems — block sums -> bsum[b]; rowptr[NN]=NE.
//   scan_fin : 49 blocks — wave0 reduces bsum[0..b), 64-lane shfl_up inclusive
//              scan + cross-wave LDS fixup, int4 stores of rowptr.
// ---------------------------------------------------------------------------
constexpr int SCAN_NB = 49;   // 49*1024 = 50176 >= NN; NN%4==0 so int4 ok

__global__ __launch_bounds__(256) void scan_part(const int* __restrict__ cnt,
                                                 int* __restrict__ bsum,
                                                 int* __restrict__ rowptr)
{
    int b = blockIdx.x, t = threadIdx.x;
    int base = b * 1024 + t * 4;
    int4 v;
    if (base < NN) v = *(const int4*)(cnt + base);
    else { v.x = 0; v.y = 0; v.z = 0; v.w = 0; }
    int s = v.x + v.y + v.z + v.w;
#pragma unroll
    for (int off = 1; off < 64; off <<= 1) s += __shfl_xor(s, off);
    __shared__ int sm[4];
    int lane = t & 63, w = t >> 6;
    if (lane == 0) sm[w] = s;
    __syncthreads();
    if (t == 0) bsum[b] = sm[0] + sm[1] + sm[2] + sm[3];
    if (b == 0 && t == 0) rowptr[NN] = NE;   // counts always sum to NE
}

__global__ __launch_bounds__(256) void scan_fin(const int* __restrict__ cnt,
                                                const int* __restrict__ bsum,
                                                int* __restrict__ rowptr)
{
    int b = blockIdx.x, t = threadIdx.x;
    int lane = t & 63, w = t >> 6;
    __shared__ int s_boff;
    __shared__ int wsum[4];
    if (w == 0) {
        int pre = (lane < b) ? bsum[lane] : 0;   // b <= 48 < 64
#pragma unroll
        for (int off = 1; off < 64; off <<= 1) pre += __shfl_xor(pre, off);
        if (lane == 0) s_boff = pre;
    }
    int base = b * 1024 + t * 4;
    int4 v;
    if (base < NN) v = *(const int4*)(cnt + base);
    else { v.x = 0; v.y = 0; v.z = 0; v.w = 0; }
    int s = v.x + v.y + v.z + v.w;
    int inc = s;
#pragma unroll
    for (int off = 1; off < 64; off <<= 1) {
        int u = __shfl_up(inc, off);
        if (lane >= off) inc += u;
    }
    if (lane == 63) wsum[w] = inc;
    __syncthreads();
    int run = s_boff + (inc - s);
#pragma unroll
    for (int i = 0; i < 3; ++i) if (i < w) run += wsum[i];
    if (base < NN) {
        int4 rp;
        rp.x = run;
        rp.y = rp.x + v.x;
        rp.z = rp.y + v.y;
        rp.w = rp.z + v.z;
        *(int4*)(rowptr + base) = rp;
    }
}

// ---------------------------------------------------------------------------
// node_gemm (+fused csr_fill): blocks [0,3125) GEMM, [3125,6250) fill.
// GEMM: D[50000 x 640] = x @ Wcat + bcat (MFMA); x read directly.
// csr_fill is atomic-free: pos = rowptr[d] + rank[e].
// Epilogue LDS-STAGED (R8 win): padded LDS tile then coalesced uint4 stores.
// Outputs: qb_dst row (f16, 512B) = [q 128ch | b' 128ch];
//          ka_src row (f16, 512B) = [k 128ch | a 128ch]; vf8 row 128B (fp8).
// ---------------------------------------------------------------------------
constexpr int NG_GEMM = 3125;   // NN/16
constexpr int NG_FILL = 3125;   // NE/256

__global__ __launch_bounds__(256) void node_gemm(
    const void* __restrict__ x, const unsigned* __restrict__ gw,
    const bf16* __restrict__ WcatT,
    const float* __restrict__ bcat,
    unsigned char* __restrict__ qb_dst, unsigned char* __restrict__ ka_src,
    unsigned char* __restrict__ vf8,
    const void* __restrict__ eia, const void* __restrict__ eib, int split,
    const int* __restrict__ rowptr, const int* __restrict__ rank,
    int* __restrict__ ssrc)
{
    __shared__ _Float16 qbs[16][264];        // 528B row stride (16B-aligned)
    __shared__ _Float16 kas[16][264];
    __shared__ unsigned char vfs[16][144];   // 144B row stride

    if (blockIdx.x >= NG_GEMM) {
        // ---- csr_fill (atomic-free) ----
        const bool i64 = probe_i64(eia);
        long long e = (long long)(blockIdx.x - NG_GEMM) * 256 + threadIdx.x;
        int s = ld_idx(eia, e, i64);
        int d = split ? ld_idx(eib, e, i64) : ld_idx(eia, NE + e, i64);
        int pos = rowptr[d] + rank[e];
        ssrc[pos] = s;
        return;
    }
    const bool f32 = (gw[0] == F32_ONE);
    int wave = threadIdx.x >> 6;
    int lane = threadIdx.x & 63;
    int quad = lane >> 4;
    int l16  = lane & 15;
    int row_base = blockIdx.x * 16;
    int m = row_base + l16;

    short8 a0 = ld_xrow(x, f32, m, quad * 8);
    short8 a1 = ld_xrow(x, f32, m, 32 + quad * 8);

#pragma unroll
    for (int t = 0; t < 10; ++t) {
        int colbase = wave * 160 + t * 16;
        const bf16* bp = WcatT + (size_t)(colbase + l16) * IC + quad * 8;
        short8 b0 = *(const short8*)(bp);
        short8 b1 = *(const short8*)(bp + 32);
        f32x4 acc = {0.f, 0.f, 0.f, 0.f};
        acc = __builtin_amdgcn_mfma_f32_16x16x32_bf16(a0, b0, acc, 0, 0, 0);
        acc = __builtin_amdgcn_mfma_f32_16x16x32_bf16(a1, b1, acc, 0, 0, 0);

        float bias = bcat[colbase + l16];
        int sel = colbase >> 7;
        int cc  = (colbase & 127) + l16;
#pragma unroll
        for (int r = 0; r < 4; ++r) {
            int l = quad * 4 + r;   // row within tile
            float fv = acc[r] + bias;
            if (sel == 2) {
                vfs[l][cc] = f32_to_fp8(fv);
            } else {
                _Float16 val = (_Float16)fv;
                if (sel == 0)      qbs[l][cc] = val;
                else if (sel == 1) kas[l][cc] = val;
                else if (sel == 3) kas[l][128 + cc] = val;
                else               qbs[l][128 + cc] = val;
            }
        }
    }
    __syncthreads();

    // coalesced copy-out: qb/ka 512 uint4 each (2/thread), vf8 128 uint4
    int tix = threadIdx.x;
#pragma unroll
    for (int j = 0; j < 2; ++j) {
        int i = tix + j * 256;
        int row = i >> 5, idx = i & 31;
        *(uint4*)(qb_dst + (size_t)(row_base + row) * 512 + idx * 16) =
            *(const uint4*)((const char*)&qbs[row][0] + idx * 16);
        *(uint4*)(ka_src + (size_t)(row_base + row) * 512 + idx * 16) =
            *(const uint4*)((const char*)&kas[row][0] + idx * 16);
    }
    if (tix < 128) {
        int row = tix >> 3, idx = tix & 7;
        *(uint4*)(vf8 + (size_t)(row_base + row) * OC + idx * 16) =
            *(const uint4*)((const char*)&vfs[row][0] + idx * 16);
    }
}

// ---------------------------------------------------------------------------
// edge_gather: FUSED edge logit + softmax-weighted aggregation, 2-edge ILP.
// R9 STATIC one-node-per-wave assignment (measured optimum: 77us; R11 atomic
// queue 700us, R12 grid-stride 89us — scheduling experiments closed).
// 16-lane-partition + single-instruction DPP-add allreduce; wave-uniform
// values (beg/end, every ssrc index) in SGPRs via readfirstlane.
// Epilogue folds the s-reduction in (proven correct in R11/R12): block LDS
// reduce + one fire-and-forget 4-lane atomicAdd per block — deletes the
// s_reduce dispatch + spart round-trip.
// ---------------------------------------------------------------------------
__global__ __launch_bounds__(256) void edge_gather(
    const int* __restrict__ rowptr, const int* __restrict__ ssrc,
    unsigned char* __restrict__ qb_dst, const unsigned char* __restrict__ ka_src,
    const unsigned char* __restrict__ vf8,
    const unsigned* __restrict__ We2h, const float* __restrict__ be2f,
    float* __restrict__ ssum)
{
    int node = rfl(blockIdx.x * 4 + (threadIdx.x >> 6));
    int lane = threadIdx.x & 63;
    int i16  = lane & 15;
    int myh  = lane >> 4;

    // dst-row data: q pair for t, b' 8ch for gate
    const unsigned char* drow = qb_dst + (size_t)node * 512;
    h2 dq = u2h(*(const unsigned*)(drow + lane * 4));
    uint4 dbu = *(const uint4*)(drow + 256 + 16 * i16);
    h2 db0 = u2h(dbu.x), db1 = u2h(dbu.y), db2 = u2h(dbu.z), db3 = u2h(dbu.w);

    // gate weights for this lane's 8 channels, head myh
    uint4 wu = *(const uint4*)(We2h + lane * 4);
    h2 w0 = u2h(wu.x), w1 = u2h(wu.y), w2 = u2h(wu.z), w3 = u2h(wu.w);
    float be2h = be2f[myh];

    int beg = rfl(rowptr[node]);
    int end = rfl(rowptr[node + 1]);
    float o0 = 0.f, o1 = 0.f, s_acc = 0.f;

    if (beg < end) {
        int ib = (beg + 1 < end) ? beg + 1 : end - 1;
        int sa = rfl(ssrc[beg]);
        int sb = rfl(ssrc[ib]);
        const unsigned char* ra = ka_src + (size_t)sa * 512;
        const unsigned char* rb = ka_src + (size_t)sb * 512;
        unsigned kuA = *(const unsigned*)(ra + lane * 4);
        uint4    auA = *(const uint4*)(ra + 256 + 16 * i16);
        unsigned uvA = *(const unsigned short*)(vf8 + (size_t)sa * OC + 2 * lane);
        unsigned kuB = *(const unsigned*)(rb + lane * 4);
        uint4    auB = *(const uint4*)(rb + 256 + 16 * i16);
        unsigned uvB = *(const unsigned short*)(vf8 + (size_t)sb * OC + 2 * lane);
        int na = (beg + 2 < end) ? beg + 2 : end - 1;
        int nb = (beg + 3 < end) ? beg + 3 : end - 1;
        int sna = rfl(ssrc[na]);
        int snb = rfl(ssrc[nb]);

        for (int p = beg; p < end; p += 2) {
            // issue next-pair row loads (indices already resident, SGPR bases)
            const unsigned char* rc = ka_src + (size_t)sna * 512;
            const unsigned char* rd = ka_src + (size_t)snb * 512;
            unsigned kuC = *(const unsigned*)(rc + lane * 4);
            uint4    auC = *(const uint4*)(rc + 256 + 16 * i16);
            unsigned uvC = *(const unsigned short*)(vf8 + (size_t)sna * OC + 2 * lane);
            unsigned kuD = *(const unsigned*)(rd + lane * 4);
            uint4    auD = *(const uint4*)(rd + 256 + 16 * i16);
            unsigned uvD = *(const unsigned short*)(vf8 + (size_t)snb * OC + 2 * lane);
            // indices for pair p+4 (consumed next iteration) — scalar loads
            int fa = (p + 4 < end) ? p + 4 : end - 1;
            int fb = (p + 5 < end) ? p + 5 : end - 1;
            int s4a = rfl(ssrc[fa]);
            int s4b = rfl(ssrc[fb]);

            bool hasB = (p + 1 < end);

            // t partials (2 ch each)
            float tA = fdot2(u2h(kuA), dq, 0.f);
            float tB = fdot2(u2h(kuB), dq, 0.f);
            // gate partials (8 ch each, head myh)
            h2 hA0 = relu2(u2h(auA.x) + db0);
            h2 hA1 = relu2(u2h(auA.y) + db1);
            h2 hA2 = relu2(u2h(auA.z) + db2);
            h2 hA3 = relu2(u2h(auA.w) + db3);
            h2 hB0 = relu2(u2h(auB.x) + db0);
            h2 hB1 = relu2(u2h(auB.y) + db1);
            h2 hB2 = relu2(u2h(auB.z) + db2);
            h2 hB3 = relu2(u2h(auB.w) + db3);
            float pA = fdot2(hA3, w3, fdot2(hA2, w2, fdot2(hA1, w1, fdot2(hA0, w0, 0.f))));
            float pB = fdot2(hB3, w3, fdot2(hB2, w2, fdot2(hB1, w1, fdot2(hB0, w0, 0.f))));

            // 16-lane allreduce, single-instruction DPP adds (interleaved ILP)
            DPPFADD(tA, "quad_perm:[1,0,3,2]");  DPPFADD(pA, "quad_perm:[1,0,3,2]");
            DPPFADD(tB, "quad_perm:[1,0,3,2]");  DPPFADD(pB, "quad_perm:[1,0,3,2]");
            DPPFADD(tA, "quad_perm:[2,3,0,1]");  DPPFADD(pA, "quad_perm:[2,3,0,1]");
            DPPFADD(tB, "quad_perm:[2,3,0,1]");  DPPFADD(pB, "quad_perm:[2,3,0,1]");
            DPPFADD(tA, "row_ror:8");            DPPFADD(pA, "row_ror:8");
            DPPFADD(tB, "row_ror:8");            DPPFADD(pB, "row_ror:8");
            DPPFADD(tA, "row_ror:4");            DPPFADD(pA, "row_ror:4");
            DPPFADD(tB, "row_ror:4");            DPPFADD(pB, "row_ror:4");

            float coefA = exp2f(tA * (pA + be2h) * KC);
            float coefB = hasB ? exp2f(tB * (pB + be2h) * KC) : 0.f;
            s_acc += coefA + coefB;

            float vA0, vA1, vB0, vB1;
            fp8x2_to_f32(uvA, vA0, vA1);
            fp8x2_to_f32(uvB, vB0, vB1);
            o0 = fmaf(coefA, vA0, fmaf(coefB, vB0, o0));
            o1 = fmaf(coefA, vA1, fmaf(coefB, vB1, o1));

            kuA = kuC; auA = auC; uvA = uvC;
            kuB = kuD; auB = auD; uvB = uvD;
            sna = s4a; snb = s4b;
        }
    }
    // write agg row (bf16, 256B) into first half of this node's qb row
    *(unsigned*)(qb_dst + (size_t)node * 512 + lane * 4) = f2bu(o0) | (f2bu(o1) << 16);

    // fused s-reduction: wave w deposits its 4 head sums, 4 atomics/block
    __shared__ float sm[4][4];
    int w = threadIdx.x >> 6;
    if (i16 == 0) sm[w][myh] = s_acc;
    __syncthreads();
    if (threadIdx.x < 4) {
        float tot = sm[0][threadIdx.x] + sm[1][threadIdx.x] +
                    sm[2][threadIdx.x] + sm[3][threadIdx.x];
        atomicAdd(&ssum[threadIdx.x], tot);
    }
}

// ---------------------------------------------------------------------------
// out_gemm: MFMA out GEMM + fused softmax-normalization + fused LN.
// Agg rows live at stride 512 B inside qb_dst (first half of each row).
// ---------------------------------------------------------------------------
__global__ __launch_bounds__(256) void out_gemm(
    const unsigned char* __restrict__ aggv, const bf16* __restrict__ WoT,
    const void* __restrict__ bo, const void* __restrict__ gamma,
    const void* __restrict__ beta, const unsigned* __restrict__ gw,
    const float* __restrict__ ssum,
    void* __restrict__ out)
{
    const bool f32 = (gw[0] == F32_ONE);
    int wave = threadIdx.x >> 6;
    int lane = threadIdx.x & 63;
    int quad = lane >> 4;
    int l16  = lane & 15;
    int rb = blockIdx.x * 64 + wave * 16;
    int m = rb + l16;
    int ma = (m < NN) ? m : 0;

    const bf16* arow = (const bf16*)(aggv + (size_t)ma * 512);
    short8 a[4];
#pragma unroll
    for (int h = 0; h < 4; ++h) {
        short8 raw = *(const short8*)(arow + h * 32 + quad * 8);
        float invh = 1.0f / ssum[h];
#pragma unroll
        for (int jj = 0; jj < 8; ++jj) {
            float f = __uint_as_float(((unsigned)(unsigned short)raw[jj]) << 16) * invh;
            raw[jj] = (short)f2bu(f);
        }
        a[h] = raw;
    }

    float o[8][4];
#pragma unroll
    for (int t = 0; t < 8; ++t) {
        const bf16* bp = WoT + (size_t)(t * 16 + l16) * OC + quad * 8;
        f32x4 acc = {0.f, 0.f, 0.f, 0.f};
#pragma unroll
        for (int h = 0; h < 4; ++h) {
            short8 bfr = *(const short8*)(bp + h * 32);
            acc = __builtin_amdgcn_mfma_f32_16x16x32_bf16(a[h], bfr, acc, 0, 0, 0);
        }
        float bias = ldf(bo, t * 16 + l16, f32);
#pragma unroll
        for (int r = 0; r < 4; ++r) o[t][r] = acc[r] + bias;
    }

#pragma unroll
    for (int r = 0; r < 4; ++r) {
        float s1 = 0.f, s2 = 0.f;
#pragma unroll
        for (int t = 0; t < 8; ++t) { s1 += o[t][r]; s2 += o[t][r] * o[t][r]; }
#pragma unroll
        for (int off = 1; off <= 8; off <<= 1) {
            s1 += __shfl_xor(s1, off);
            s2 += __shfl_xor(s2, off);
        }
        float mu = s1 * (1.0f / OC);
        float var = fmaxf(s2 * (1.0f / OC) - mu * mu, 0.f);
        float rs = rsqrtf(var + 1e-5f);
        int node = rb + quad * 4 + r;
        if (node < NN) {
#pragma unroll
            for (int t = 0; t < 8; ++t) {
                int col = t * 16 + l16;
                float y = (o[t][r] - mu) * rs * ldf(gamma, col, f32) + ldf(beta, col, f32);
                if (f32) ((float*)out)[(size_t)node * OC + col] = y;
                else     ((bf16*)out)[(size_t)node * OC + col] = __float2bfloat16(y);
            }
        }
    }
}

// ---------------------------------------------------------------------------
extern "C" void kernel_launch(void* const* d_in, const int* in_sizes, int n_in,
                              void* d_out, int out_size, void* d_ws, size_t ws_size,
                              hipStream_t stream)
{
    int p = 0;
    const void* x   = d_in[p++];
    const void* eia = d_in[p++];
    const void* eib = eia;
    int split = 0;
    if (n_in >= 17) { eib = d_in[p++]; split = 1; }
    const void* Wq   = d_in[p++];
    const void* bq   = d_in[p++];
    const void* Wk   = d_in[p++];
    const void* bk   = d_in[p++];
    const void* Wv   = d_in[p++];
    const void* bv   = d_in[p++];
    const void* We1  = d_in[p++];
    const void* be1  = d_in[p++];
    const void* We2  = d_in[p++];
    const void* be2  = d_in[p++];
    const void* Wo   = d_in[p++];
    const void* bo   = d_in[p++];
    const void* gamma= d_in[p++];
    const void* beta = d_in[p++];
    const unsigned* gw = (const unsigned*)gamma;

    // workspace layout (~64 MB). cnt+ssum adjacent -> single memset.
    char* w = (char*)d_ws;
    unsigned char* qb_dst = (unsigned char*)w; w += (size_t)NN * 512;     // 25.6 MB (f16 q|b')
    unsigned char* ka_src = (unsigned char*)w; w += (size_t)NN * 512;     // 25.6 MB (f16 k|a)
    unsigned char* vf8    = (unsigned char*)w; w += (size_t)NN * OC;      // 6.4 MB
    int*   ssrc   = (int*)w;                   w += (size_t)NE * 4;       // 3.2 MB
    int*   rank   = (int*)w;                   w += (size_t)NE * 4;       // 3.2 MB
    int*   cnt    = (int*)w;                   w += (size_t)NN * 4;       // 200 KB
    float* ssum   = (float*)w;                 w += 8 * 4;                // zeroed w/ cnt
    int*   rowptr = (int*)w;                   w += (size_t)(NN + 4) * 4; // padded to 16B
    int*   bsum   = (int*)w;                   w += 64 * 4;               // scan block sums
    unsigned* We2h = (unsigned*)w;             w += 256 * 4;              // 1 KB
    float* be2f   = (float*)w;                 w += NH * 4;
    bf16*  WcatT  = (bf16*)w;                  w += (size_t)5 * OC * IC * 2;
    float* bcat   = (float*)w;                 w += 5 * OC * 4;
    bf16*  WoT    = (bf16*)w;                  w += (size_t)OC * OC * 2;

    if (ws_size < (size_t)((char*)w - (char*)d_ws)) return;

    hipMemsetAsync(cnt, 0, (size_t)NN * 4 + 32, stream);   // cnt + ssum
    prep<<<PB_W + PB_WO + PB_CNT + 1, 256, 0, stream>>>(
        Wq, bq, Wk, bk, Wv, bv, We1, be1, We2, be2, Wo, gw,
        eia, eib, split,
        WcatT, WoT, cnt, rank, We2h, be2f, bcat);
    scan_part<<<SCAN_NB, 256, 0, stream>>>(cnt, bsum, rowptr);
    scan_fin<<<SCAN_NB, 256, 0, stream>>>(cnt, bsum, rowptr);
    node_gemm<<<NG_GEMM + NG_FILL, 256, 0, stream>>>(
        x, gw, WcatT, bcat, qb_dst, ka_src, vf8, eia, eib, split, rowptr, rank, ssrc);
    edge_gather<<<NN / 4, 256, 0, stream>>>(rowptr, ssrc, qb_dst, ka_src, vf8,
                                            We2h, be2f, ssum);
    out_gemm<<<(NN + 63) / 64, 256, 0, stream>>>(qb_dst, WoT, bo, gamma, beta, gw,
                                                 ssum, d_out);
}

// Round 14
// 286.201 us; speedup vs baseline: 1.3513x; 1.3513x over previous
//
#include <hip/hip_runtime.h>
#include <hip/hip_bf16.h>

typedef __hip_bfloat16 bf16;
typedef __attribute__((ext_vector_type(8))) short short8;   // 8 bf16 (4 VGPRs)
typedef __attribute__((ext_vector_type(4))) float f32x4;    // 4 fp32 acc
typedef __attribute__((ext_vector_type(2))) float f32x2;
typedef _Float16 h2 __attribute__((ext_vector_type(2)));    // packed half2

constexpr int NN = 50000;   // nodes
constexpr int NE = 800000;  // edges
constexpr int IC = 64;      // in channels
constexpr int OC = 128;     // out channels
constexpr int NH = 4;       // heads
constexpr unsigned F32_ONE = 0x3F800000u;
// 1/sqrt(32) * log2(e): exp(l) = exp2(l*log2e), constants fused
constexpr float KC = 0.25503486f;

__device__ __forceinline__ float ldf(const void* p, int i, bool f32) {
    return f32 ? ((const float*)p)[i]
               : __bfloat162float(((const bf16*)p)[i]);
}

__device__ __forceinline__ int ld_idx(const void* p, long long i, bool i64) {
    return i64 ? (int)((const long long*)p)[i] : ((const int*)p)[i];
}

__device__ __forceinline__ bool probe_i64(const void* ei) {
    const unsigned* u = (const unsigned*)ei;
    return (u[1] | u[3] | u[5] | u[7]) == 0u;
}

// f32 -> bf16 bits (RNE)
__device__ __forceinline__ unsigned f2bu(float x) {
    unsigned u = __float_as_uint(x);
    return (u + 0x7FFFu + ((u >> 16) & 1u)) >> 16;
}

__device__ __forceinline__ h2 u2h(unsigned u) { return __builtin_bit_cast(h2, u); }

// dot2: c += a[0]*b[0] + a[1]*b[1] (f16 inputs, f32 accum)
__device__ __forceinline__ float fdot2(h2 a, h2 b, float c) {
#if __has_builtin(__builtin_amdgcn_fdot2)
    return __builtin_amdgcn_fdot2(a, b, c, false);
#else
    return c + (float)a[0] * (float)b[0] + (float)a[1] * (float)b[1];
#endif
}

__device__ __forceinline__ h2 relu2(h2 a) {
    h2 z = {(_Float16)0.f, (_Float16)0.f};
#if __has_builtin(__builtin_elementwise_max)
    return __builtin_elementwise_max(a, z);
#else
    h2 r;
    r[0] = a[0] > (_Float16)0.f ? a[0] : (_Float16)0.f;
    r[1] = a[1] > (_Float16)0.f ? a[1] : (_Float16)0.f;
    return r;
#endif
}

// Single-instruction DPP add: x = dpp(x) + x (VOP2 DPP encoding).
// ctrl strings: xor1 = quad_perm:[1,0,3,2], xor2 = quad_perm:[2,3,0,1],
// xor8-in-row = row_ror:8, xor4-in-row = row_ror:4 (full 16-lane allreduce).
#define DPPFADD(x, ctrl) \
    asm("v_add_f32 %0, %0, %0 " ctrl " row_mask:0xf bank_mask:0xf" : "+v"(x))

// wave-uniform value -> SGPR (compiler can't prove threadIdx.x>>6 uniform)
__device__ __forceinline__ int rfl(int v) { return __builtin_amdgcn_readfirstlane(v); }

// x-row fragment load: bf16 input -> direct short8; f32 input -> float4 pair
// + one-time RNE convert (same rounding as __float2bfloat16).
__device__ __forceinline__ short8 ld_xrow(const void* x, bool f32, int m, int off) {
    if (!f32) return *(const short8*)((const bf16*)x + (size_t)m * IC + off);
    const float* xr = (const float*)x + (size_t)m * IC + off;
    float4 u0 = *(const float4*)xr;
    float4 u1 = *(const float4*)(xr + 4);
    short8 r;
    r[0] = (short)f2bu(u0.x); r[1] = (short)f2bu(u0.y);
    r[2] = (short)f2bu(u0.z); r[3] = (short)f2bu(u0.w);
    r[4] = (short)f2bu(u1.x); r[5] = (short)f2bu(u1.y);
    r[6] = (short)f2bu(u1.z); r[7] = (short)f2bu(u1.w);
    return r;
}

// ---- fp8 e4m3 helpers ------------------------------------------------------
__device__ __forceinline__ unsigned char f32_to_fp8(float x) {
#if __has_builtin(__builtin_amdgcn_cvt_pk_fp8_f32)
    return (unsigned char)(__builtin_amdgcn_cvt_pk_fp8_f32(x, x, 0, false) & 0xFF);
#else
    unsigned bits = __float_as_uint(x);
    unsigned s = bits >> 31;
    float a = fabsf(x);
    if (a >= 448.f) return (unsigned char)((s << 7) | 0x7E);
    if (a < 0.015625f) {
        int m = (int)(a * 512.f + 0.5f);
        if (m >= 8) return (unsigned char)((s << 7) | 0x08);
        return (unsigned char)((s << 7) | m);
    }
    unsigned ab = (bits & 0x7FFFFFFFu) + 0x00080000u;
    int e8 = (int)(ab >> 23) - 127 + 7;
    unsigned m3 = (ab >> 20) & 7u;
    if (e8 >= 16) return (unsigned char)((s << 7) | 0x7E);
    return (unsigned char)((s << 7) | ((unsigned)e8 << 3) | m3);
#endif
}

__device__ __forceinline__ void fp8x2_to_f32(unsigned u, float& f0, float& f1) {
#if __has_builtin(__builtin_amdgcn_cvt_pk_f32_fp8)
    f32x2 lo = __builtin_amdgcn_cvt_pk_f32_fp8(u, false);
    f0 = lo[0]; f1 = lo[1];
#else
    float r[2];
#pragma unroll
    for (int j = 0; j < 2; ++j) {
        unsigned b = (u >> (8 * j)) & 0xFF;
        unsigned s = b >> 7, e = (b >> 3) & 15, m = b & 7;
        float v = (e == 0) ? (float)m * 0.001953125f
                           : __uint_as_float(((e + 120u) << 23) | (m << 20));
        r[j] = s ? -v : v;
    }
    f0 = r[0]; f1 = r[1];
#endif
}

// ---------------------------------------------------------------------------
// prep: weight conversions + csr_count. (cnt/ssum zeroed by memset)
// Counting atomicAdd's return value = edge's rank within dst bucket -> rank[e];
// csr_fill then needs NO atomics: pos = rowptr[d] + rank[e].
// bcat: [0,128)=bq, [128,256)=bk, [256,384)=bv, [384,512)=0 (a), [512,640)=be1 (b')
// We2h packing (edge_gather 16-lane scheme, R4 layout): entry t = lane*4 + k,
//   lane: g = lane>>4 (head), i = lane&15; pair index pp = 4*i + k;
//   value = half2( We2[2pp][g], We2[2pp+1][g] ).
// ---------------------------------------------------------------------------
constexpr int PB_W   = 160;
constexpr int PB_WO  = 64;
constexpr int PB_CNT = 3125;   // csr_count: NE/256

__global__ __launch_bounds__(256) void prep(
    const void* __restrict__ Wq, const void* __restrict__ bq,
    const void* __restrict__ Wk, const void* __restrict__ bk,
    const void* __restrict__ Wv, const void* __restrict__ bv,
    const void* __restrict__ We1, const void* __restrict__ be1,
    const void* __restrict__ We2, const void* __restrict__ be2,
    const void* __restrict__ Wo,  const unsigned* __restrict__ gw,
    const void* __restrict__ eia, const void* __restrict__ eib, int split,
    bf16* __restrict__ WcatT, bf16* __restrict__ WoT,
    int* __restrict__ cnt, int* __restrict__ rank,
    unsigned* __restrict__ We2h, float* __restrict__ be2f,
    float* __restrict__ bcat)
{
    const bool f32 = (gw[0] == F32_ONE);
    int b = blockIdx.x, t = threadIdx.x;
    if (b < PB_W) {
        int idx = b * 256 + t;                  // n*64 + k
        int n = idx >> 6, k = idx & 63;
        int sel = n >> 7, c = n & 127;
        float v;
        if (sel == 0)      v = ldf(Wq, k * OC + c, f32);
        else if (sel == 1) v = ldf(Wk, k * OC + c, f32);
        else if (sel == 2) v = ldf(Wv, k * OC + c, f32);
        else if (sel == 3) v = ldf(We1, k * OC + c, f32);
        else               v = ldf(We1, (IC + k) * OC + c, f32);
        WcatT[idx] = __float2bfloat16(v);
    } else if (b < PB_W + PB_WO) {
        int idx = (b - PB_W) * 256 + t;         // n*128 + k
        int n = idx >> 7, k = idx & 127;
        WoT[idx] = __float2bfloat16(ldf(Wo, k * OC + n, f32));
    } else if (b < PB_W + PB_WO + PB_CNT) {
        const bool i64 = probe_i64(eia);
        long long e = (long long)(b - PB_W - PB_WO) * 256 + t;
        int d = split ? ld_idx(eib, e, i64) : ld_idx(eia, NE + e, i64);
        int r = atomicAdd(&cnt[d], 1);
        rank[e] = r;
    } else {
        if (t < NH) be2f[t] = ldf(be2, t, f32);
        // We2h: 64 lanes x 4 dwords, per-lane 8-channel weight slice for ONE head
        {
            int ln = t >> 2, k = t & 3;         // t in [0,256)
            int g = ln >> 4, ii = ln & 15;
            int pp = 4 * ii + k;
            h2 hv;
            hv[0] = (_Float16)ldf(We2, (2 * pp) * NH + g, f32);
            hv[1] = (_Float16)ldf(We2, (2 * pp + 1) * NH + g, f32);
            We2h[t] = __builtin_bit_cast(unsigned, hv);
        }
        for (int n = t; n < 5 * OC; n += 256) {
            int sel = n >> 7, c = n & 127;
            float bb = 0.f;
            if (sel == 0) bb = ldf(bq, c, f32);
            else if (sel == 1) bb = ldf(bk, c, f32);
            else if (sel == 2) bb = ldf(bv, c, f32);
            else if (sel == 4) bb = ldf(be1, c, f32);  // fold be1 into b'
            bcat[n] = bb;
        }
    }
}

// ---------------------------------------------------------------------------
// Parallel CSR scan:
//   scan_part: 49 blocks x 1024 elems — block sums -> bsum[b]; rowptr[NN]=NE.
//   scan_fin : 49 blocks — wave0 reduces bsum[0..b), 64-lane shfl_up inclusive
//              scan + cross-wave LDS fixup, int4 stores of rowptr.
// ---------------------------------------------------------------------------
constexpr int SCAN_NB = 49;   // 49*1024 = 50176 >= NN; NN%4==0 so int4 ok

__global__ __launch_bounds__(256) void scan_part(const int* __restrict__ cnt,
                                                 int* __restrict__ bsum,
                                                 int* __restrict__ rowptr)
{
    int b = blockIdx.x, t = threadIdx.x;
    int base = b * 1024 + t * 4;
    int4 v;
    if (base < NN) v = *(const int4*)(cnt + base);
    else { v.x = 0; v.y = 0; v.z = 0; v.w = 0; }
    int s = v.x + v.y + v.z + v.w;
#pragma unroll
    for (int off = 1; off < 64; off <<= 1) s += __shfl_xor(s, off);
    __shared__ int sm[4];
    int lane = t & 63, w = t >> 6;
    if (lane == 0) sm[w] = s;
    __syncthreads();
    if (t == 0) bsum[b] = sm[0] + sm[1] + sm[2] + sm[3];
    if (b == 0 && t == 0) rowptr[NN] = NE;   // counts always sum to NE
}

__global__ __launch_bounds__(256) void scan_fin(const int* __restrict__ cnt,
                                                const int* __restrict__ bsum,
                                                int* __restrict__ rowptr)
{
    int b = blockIdx.x, t = threadIdx.x;
    int lane = t & 63, w = t >> 6;
    __shared__ int s_boff;
    __shared__ int wsum[4];
    if (w == 0) {
        int pre = (lane < b) ? bsum[lane] : 0;   // b <= 48 < 64
#pragma unroll
        for (int off = 1; off < 64; off <<= 1) pre += __shfl_xor(pre, off);
        if (lane == 0) s_boff = pre;
    }
    int base = b * 1024 + t * 4;
    int4 v;
    if (base < NN) v = *(const int4*)(cnt + base);
    else { v.x = 0; v.y = 0; v.z = 0; v.w = 0; }
    int s = v.x + v.y + v.z + v.w;
    int inc = s;
#pragma unroll
    for (int off = 1; off < 64; off <<= 1) {
        int u = __shfl_up(inc, off);
        if (lane >= off) inc += u;
    }
    if (lane == 63) wsum[w] = inc;
    __syncthreads();
    int run = s_boff + (inc - s);
#pragma unroll
    for (int i = 0; i < 3; ++i) if (i < w) run += wsum[i];
    if (base < NN) {
        int4 rp;
        rp.x = run;
        rp.y = rp.x + v.x;
        rp.z = rp.y + v.y;
        rp.w = rp.z + v.z;
        *(int4*)(rowptr + base) = rp;
    }
}

// ---------------------------------------------------------------------------
// node_gemm (+fused csr_fill): blocks [0,3125) GEMM, [3125,6250) fill.
// GEMM: D[50000 x 640] = x @ Wcat + bcat (MFMA); x read directly.
// csr_fill is atomic-free: pos = rowptr[d] + rank[e].
// Epilogue LDS-STAGED (R8 win): padded LDS tile then coalesced uint4 stores.
// Outputs: qb_dst row (f16, 512B) = [q 128ch | b' 128ch];
//          ka_src row (f16, 512B) = [k 128ch | a 128ch]; vf8 row 128B (fp8).
// ---------------------------------------------------------------------------
constexpr int NG_GEMM = 3125;   // NN/16
constexpr int NG_FILL = 3125;   // NE/256

__global__ __launch_bounds__(256) void node_gemm(
    const void* __restrict__ x, const unsigned* __restrict__ gw,
    const bf16* __restrict__ WcatT,
    const float* __restrict__ bcat,
    unsigned char* __restrict__ qb_dst, unsigned char* __restrict__ ka_src,
    unsigned char* __restrict__ vf8,
    const void* __restrict__ eia, const void* __restrict__ eib, int split,
    const int* __restrict__ rowptr, const int* __restrict__ rank,
    int* __restrict__ ssrc)
{
    __shared__ _Float16 qbs[16][264];        // 528B row stride (16B-aligned)
    __shared__ _Float16 kas[16][264];
    __shared__ unsigned char vfs[16][144];   // 144B row stride

    if (blockIdx.x >= NG_GEMM) {
        // ---- csr_fill (atomic-free) ----
        const bool i64 = probe_i64(eia);
        long long e = (long long)(blockIdx.x - NG_GEMM) * 256 + threadIdx.x;
        int s = ld_idx(eia, e, i64);
        int d = split ? ld_idx(eib, e, i64) : ld_idx(eia, NE + e, i64);
        int pos = rowptr[d] + rank[e];
        ssrc[pos] = s;
        return;
    }
    const bool f32 = (gw[0] == F32_ONE);
    int wave = threadIdx.x >> 6;
    int lane = threadIdx.x & 63;
    int quad = lane >> 4;
    int l16  = lane & 15;
    int row_base = blockIdx.x * 16;
    int m = row_base + l16;

    short8 a0 = ld_xrow(x, f32, m, quad * 8);
    short8 a1 = ld_xrow(x, f32, m, 32 + quad * 8);

#pragma unroll
    for (int t = 0; t < 10; ++t) {
        int colbase = wave * 160 + t * 16;
        const bf16* bp = WcatT + (size_t)(colbase + l16) * IC + quad * 8;
        short8 b0 = *(const short8*)(bp);
        short8 b1 = *(const short8*)(bp + 32);
        f32x4 acc = {0.f, 0.f, 0.f, 0.f};
        acc = __builtin_amdgcn_mfma_f32_16x16x32_bf16(a0, b0, acc, 0, 0, 0);
        acc = __builtin_amdgcn_mfma_f32_16x16x32_bf16(a1, b1, acc, 0, 0, 0);

        float bias = bcat[colbase + l16];
        int sel = colbase >> 7;
        int cc  = (colbase & 127) + l16;
#pragma unroll
        for (int r = 0; r < 4; ++r) {
            int l = quad * 4 + r;   // row within tile
            float fv = acc[r] + bias;
            if (sel == 2) {
                vfs[l][cc] = f32_to_fp8(fv);
            } else {
                _Float16 val = (_Float16)fv;
                if (sel == 0)      qbs[l][cc] = val;
                else if (sel == 1) kas[l][cc] = val;
                else if (sel == 3) kas[l][128 + cc] = val;
                else               qbs[l][128 + cc] = val;
            }
        }
    }
    __syncthreads();

    // coalesced copy-out: qb/ka 512 uint4 each (2/thread), vf8 128 uint4
    int tix = threadIdx.x;
#pragma unroll
    for (int j = 0; j < 2; ++j) {
        int i = tix + j * 256;
        int row = i >> 5, idx = i & 31;
        *(uint4*)(qb_dst + (size_t)(row_base + row) * 512 + idx * 16) =
            *(const uint4*)((const char*)&qbs[row][0] + idx * 16);
        *(uint4*)(ka_src + (size_t)(row_base + row) * 512 + idx * 16) =
            *(const uint4*)((const char*)&kas[row][0] + idx * 16);
    }
    if (tix < 128) {
        int row = tix >> 3, idx = tix & 7;
        *(uint4*)(vf8 + (size_t)(row_base + row) * OC + idx * 16) =
            *(const uint4*)((const char*)&vfs[row][0] + idx * 16);
    }
}

// ---------------------------------------------------------------------------
// edge_gather: FUSED edge logit + softmax-weighted aggregation, 2-edge ILP.
// R9 configuration — measured optimum (77us). NO block barrier anywhere:
// per-wave independent retirement IS the load-balancing mechanism (R13's
// end-of-kernel __syncthreads cost ~100us). Scheduling experiments closed
// (R11 atomic queue 700us, R12 grid-stride 89us, R13 barrier 178us).
// 16-lane-partition + single-instruction DPP-add allreduce; wave-uniform
// values (beg/end, every ssrc index) in SGPRs via readfirstlane.
// ---------------------------------------------------------------------------
__global__ __launch_bounds__(256) void edge_gather(
    const int* __restrict__ rowptr, const int* __restrict__ ssrc,
    unsigned char* __restrict__ qb_dst, const unsigned char* __restrict__ ka_src,
    const unsigned char* __restrict__ vf8,
    const unsigned* __restrict__ We2h, const float* __restrict__ be2f,
    float* __restrict__ spart)
{
    int node = rfl(blockIdx.x * 4 + (threadIdx.x >> 6));
    int lane = threadIdx.x & 63;
    int i16  = lane & 15;
    int myh  = lane >> 4;

    // dst-row data: q pair for t, b' 8ch for gate
    const unsigned char* drow = qb_dst + (size_t)node * 512;
    h2 dq = u2h(*(const unsigned*)(drow + lane * 4));
    uint4 dbu = *(const uint4*)(drow + 256 + 16 * i16);
    h2 db0 = u2h(dbu.x), db1 = u2h(dbu.y), db2 = u2h(dbu.z), db3 = u2h(dbu.w);

    // gate weights for this lane's 8 channels, head myh
    uint4 wu = *(const uint4*)(We2h + lane * 4);
    h2 w0 = u2h(wu.x), w1 = u2h(wu.y), w2 = u2h(wu.z), w3 = u2h(wu.w);
    float be2h = be2f[myh];

    int beg = rfl(rowptr[node]);
    int end = rfl(rowptr[node + 1]);
    float o0 = 0.f, o1 = 0.f, s_acc = 0.f;

    if (beg < end) {
        int ib = (beg + 1 < end) ? beg + 1 : end - 1;
        int sa = rfl(ssrc[beg]);
        int sb = rfl(ssrc[ib]);
        const unsigned char* ra = ka_src + (size_t)sa * 512;
        const unsigned char* rb = ka_src + (size_t)sb * 512;
        unsigned kuA = *(const unsigned*)(ra + lane * 4);
        uint4    auA = *(const uint4*)(ra + 256 + 16 * i16);
        unsigned uvA = *(const unsigned short*)(vf8 + (size_t)sa * OC + 2 * lane);
        unsigned kuB = *(const unsigned*)(rb + lane * 4);
        uint4    auB = *(const uint4*)(rb + 256 + 16 * i16);
        unsigned uvB = *(const unsigned short*)(vf8 + (size_t)sb * OC + 2 * lane);
        int na = (beg + 2 < end) ? beg + 2 : end - 1;
        int nb = (beg + 3 < end) ? beg + 3 : end - 1;
        int sna = rfl(ssrc[na]);
        int snb = rfl(ssrc[nb]);

        for (int p = beg; p < end; p += 2) {
            // issue next-pair row loads (indices already resident, SGPR bases)
            const unsigned char* rc = ka_src + (size_t)sna * 512;
            const unsigned char* rd = ka_src + (size_t)snb * 512;
            unsigned kuC = *(const unsigned*)(rc + lane * 4);
            uint4    auC = *(const uint4*)(rc + 256 + 16 * i16);
            unsigned uvC = *(const unsigned short*)(vf8 + (size_t)sna * OC + 2 * lane);
            unsigned kuD = *(const unsigned*)(rd + lane * 4);
            uint4    auD = *(const uint4*)(rd + 256 + 16 * i16);
            unsigned uvD = *(const unsigned short*)(vf8 + (size_t)snb * OC + 2 * lane);
            // indices for pair p+4 (consumed next iteration) — scalar loads
            int fa = (p + 4 < end) ? p + 4 : end - 1;
            int fb = (p + 5 < end) ? p + 5 : end - 1;
            int s4a = rfl(ssrc[fa]);
            int s4b = rfl(ssrc[fb]);

            bool hasB = (p + 1 < end);

            // t partials (2 ch each)
            float tA = fdot2(u2h(kuA), dq, 0.f);
            float tB = fdot2(u2h(kuB), dq, 0.f);
            // gate partials (8 ch each, head myh)
            h2 hA0 = relu2(u2h(auA.x) + db0);
            h2 hA1 = relu2(u2h(auA.y) + db1);
            h2 hA2 = relu2(u2h(auA.z) + db2);
            h2 hA3 = relu2(u2h(auA.w) + db3);
            h2 hB0 = relu2(u2h(auB.x) + db0);
            h2 hB1 = relu2(u2h(auB.y) + db1);
            h2 hB2 = relu2(u2h(auB.z) + db2);
            h2 hB3 = relu2(u2h(auB.w) + db3);
            float pA = fdot2(hA3, w3, fdot2(hA2, w2, fdot2(hA1, w1, fdot2(hA0, w0, 0.f))));
            float pB = fdot2(hB3, w3, fdot2(hB2, w2, fdot2(hB1, w1, fdot2(hB0, w0, 0.f))));

            // 16-lane allreduce, single-instruction DPP adds (interleaved ILP)
            DPPFADD(tA, "quad_perm:[1,0,3,2]");  DPPFADD(pA, "quad_perm:[1,0,3,2]");
            DPPFADD(tB, "quad_perm:[1,0,3,2]");  DPPFADD(pB, "quad_perm:[1,0,3,2]");
            DPPFADD(tA, "quad_perm:[2,3,0,1]");  DPPFADD(pA, "quad_perm:[2,3,0,1]");
            DPPFADD(tB, "quad_perm:[2,3,0,1]");  DPPFADD(pB, "quad_perm:[2,3,0,1]");
            DPPFADD(tA, "row_ror:8");            DPPFADD(pA, "row_ror:8");
            DPPFADD(tB, "row_ror:8");            DPPFADD(pB, "row_ror:8");
            DPPFADD(tA, "row_ror:4");            DPPFADD(pA, "row_ror:4");
            DPPFADD(tB, "row_ror:4");            DPPFADD(pB, "row_ror:4");

            float coefA = exp2f(tA * (pA + be2h) * KC);
            float coefB = hasB ? exp2f(tB * (pB + be2h) * KC) : 0.f;
            s_acc += coefA + coefB;

            float vA0, vA1, vB0, vB1;
            fp8x2_to_f32(uvA, vA0, vA1);
            fp8x2_to_f32(uvB, vB0, vB1);
            o0 = fmaf(coefA, vA0, fmaf(coefB, vB0, o0));
            o1 = fmaf(coefA, vA1, fmaf(coefB, vB1, o1));

            kuA = kuC; auA = auC; uvA = uvC;
            kuB = kuD; auB = auD; uvB = uvD;
            sna = s4a; snb = s4b;
        }
    }
    // write agg row (bf16, 256B) into first half of this node's qb row
    *(unsigned*)(qb_dst + (size_t)node * 512 + lane * 4) = f2bu(o0) | (f2bu(o1) << 16);
    if (i16 == 0) spart[node * 4 + myh] = s_acc;
}

// ---------------------------------------------------------------------------
// s_reduce: PARALLEL reduction of spart (NN*4) -> ssum[4] via atomics.
// ---------------------------------------------------------------------------
constexpr int SR_BLOCKS = 98;
__global__ __launch_bounds__(256) void s_reduce(const float* __restrict__ spart,
                                                float* __restrict__ ssum)
{
    int tid = blockIdx.x * 256 + threadIdx.x;
    int h = threadIdx.x & 3;
    float s = 0.f;
    for (int i = tid; i < NN * 4; i += SR_BLOCKS * 256) s += spart[i];
#pragma unroll
    for (int off = 4; off <= 32; off <<= 1) s += __shfl_xor(s, off);
    __shared__ float sm[4][4];
    int lane = threadIdx.x & 63, w = threadIdx.x >> 6;
    if (lane < 4) sm[w][h] = s;
    __syncthreads();
    if (threadIdx.x < 4) {
        float tot = sm[0][h] + sm[1][h] + sm[2][h] + sm[3][h];
        atomicAdd(&ssum[h], tot);
    }
}

// ---------------------------------------------------------------------------
// out_gemm: MFMA out GEMM + fused softmax-normalization + fused LN.
// Agg rows live at stride 512 B inside qb_dst (first half of each row).
// ---------------------------------------------------------------------------
__global__ __launch_bounds__(256) void out_gemm(
    const unsigned char* __restrict__ aggv, const bf16* __restrict__ WoT,
    const void* __restrict__ bo, const void* __restrict__ gamma,
    const void* __restrict__ beta, const unsigned* __restrict__ gw,
    const float* __restrict__ ssum,
    void* __restrict__ out)
{
    const bool f32 = (gw[0] == F32_ONE);
    int wave = threadIdx.x >> 6;
    int lane = threadIdx.x & 63;
    int quad = lane >> 4;
    int l16  = lane & 15;
    int rb = blockIdx.x * 64 + wave * 16;
    int m = rb + l16;
    int ma = (m < NN) ? m : 0;

    const bf16* arow = (const bf16*)(aggv + (size_t)ma * 512);
    short8 a[4];
#pragma unroll
    for (int h = 0; h < 4; ++h) {
        short8 raw = *(const short8*)(arow + h * 32 + quad * 8);
        float invh = 1.0f / ssum[h];
#pragma unroll
        for (int jj = 0; jj < 8; ++jj) {
            float f = __uint_as_float(((unsigned)(unsigned short)raw[jj]) << 16) * invh;
            raw[jj] = (short)f2bu(f);
        }
        a[h] = raw;
    }

    float o[8][4];
#pragma unroll
    for (int t = 0; t < 8; ++t) {
        const bf16* bp = WoT + (size_t)(t * 16 + l16) * OC + quad * 8;
        f32x4 acc = {0.f, 0.f, 0.f, 0.f};
#pragma unroll
        for (int h = 0; h < 4; ++h) {
            short8 bfr = *(const short8*)(bp + h * 32);
            acc = __builtin_amdgcn_mfma_f32_16x16x32_bf16(a[h], bfr, acc, 0, 0, 0);
        }
        float bias = ldf(bo, t * 16 + l16, f32);
#pragma unroll
        for (int r = 0; r < 4; ++r) o[t][r] = acc[r] + bias;
    }

#pragma unroll
    for (int r = 0; r < 4; ++r) {
        float s1 = 0.f, s2 = 0.f;
#pragma unroll
        for (int t = 0; t < 8; ++t) { s1 += o[t][r]; s2 += o[t][r] * o[t][r]; }
#pragma unroll
        for (int off = 1; off <= 8; off <<= 1) {
            s1 += __shfl_xor(s1, off);
            s2 += __shfl_xor(s2, off);
        }
        float mu = s1 * (1.0f / OC);
        float var = fmaxf(s2 * (1.0f / OC) - mu * mu, 0.f);
        float rs = rsqrtf(var + 1e-5f);
        int node = rb + quad * 4 + r;
        if (node < NN) {
#pragma unroll
            for (int t = 0; t < 8; ++t) {
                int col = t * 16 + l16;
                float y = (o[t][r] - mu) * rs * ldf(gamma, col, f32) + ldf(beta, col, f32);
                if (f32) ((float*)out)[(size_t)node * OC + col] = y;
                else     ((bf16*)out)[(size_t)node * OC + col] = __float2bfloat16(y);
            }
        }
    }
}

// ---------------------------------------------------------------------------
extern "C" void kernel_launch(void* const* d_in, const int* in_sizes, int n_in,
                              void* d_out, int out_size, void* d_ws, size_t ws_size,
                              hipStream_t stream)
{
    int p = 0;
    const void* x   = d_in[p++];
    const void* eia = d_in[p++];
    const void* eib = eia;
    int split = 0;
    if (n_in >= 17) { eib = d_in[p++]; split = 1; }
    const void* Wq   = d_in[p++];
    const void* bq   = d_in[p++];
    const void* Wk   = d_in[p++];
    const void* bk   = d_in[p++];
    const void* Wv   = d_in[p++];
    const void* bv   = d_in[p++];
    const void* We1  = d_in[p++];
    const void* be1  = d_in[p++];
    const void* We2  = d_in[p++];
    const void* be2  = d_in[p++];
    const void* Wo   = d_in[p++];
    const void* bo   = d_in[p++];
    const void* gamma= d_in[p++];
    const void* beta = d_in[p++];
    const unsigned* gw = (const unsigned*)gamma;

    // workspace layout (~65 MB). cnt and ssum adjacent -> single memset.
    char* w = (char*)d_ws;
    unsigned char* qb_dst = (unsigned char*)w; w += (size_t)NN * 512;     // 25.6 MB (f16 q|b')
    unsigned char* ka_src = (unsigned char*)w; w += (size_t)NN * 512;     // 25.6 MB (f16 k|a)
    unsigned char* vf8    = (unsigned char*)w; w += (size_t)NN * OC;      // 6.4 MB
    int*   ssrc   = (int*)w;                   w += (size_t)NE * 4;       // 3.2 MB
    int*   rank   = (int*)w;                   w += (size_t)NE * 4;       // 3.2 MB
    int*   cnt    = (int*)w;                   w += (size_t)NN * 4;       // 200 KB
    float* ssum   = (float*)w;                 w += 8 * 4;                // (memset w/ cnt)
    int*   rowptr = (int*)w;                   w += (size_t)(NN + 4) * 4; // padded to 16B
    int*   bsum   = (int*)w;                   w += 64 * 4;               // scan block sums
    float* spart  = (float*)w;                 w += (size_t)NN * 4 * 4;   // 800 KB
    unsigned* We2h = (unsigned*)w;             w += 256 * 4;              // 1 KB
    float* be2f   = (float*)w;                 w += NH * 4;
    bf16*  WcatT  = (bf16*)w;                  w += (size_t)5 * OC * IC * 2;
    float* bcat   = (float*)w;                 w += 5 * OC * 4;
    bf16*  WoT    = (bf16*)w;                  w += (size_t)OC * OC * 2;

    if (ws_size < (size_t)((char*)w - (char*)d_ws)) return;

    hipMemsetAsync(cnt, 0, (size_t)NN * 4 + 32, stream);   // cnt + ssum
    prep<<<PB_W + PB_WO + PB_CNT + 1, 256, 0, stream>>>(
        Wq, bq, Wk, bk, Wv, bv, We1, be1, We2, be2, Wo, gw,
        eia, eib, split,
        WcatT, WoT, cnt, rank, We2h, be2f, bcat);
    scan_part<<<SCAN_NB, 256, 0, stream>>>(cnt, bsum, rowptr);
    scan_fin<<<SCAN_NB, 256, 0, stream>>>(cnt, bsum, rowptr);
    node_gemm<<<NG_GEMM + NG_FILL, 256, 0, stream>>>(
        x, gw, WcatT, bcat, qb_dst, ka_src, vf8, eia, eib, split, rowptr, rank, ssrc);
    edge_gather<<<NN / 4, 256, 0, stream>>>(rowptr, ssrc, qb_dst, ka_src, vf8,
                                            We2h, be2f, spart);
    s_reduce<<<SR_BLOCKS, 256, 0, stream>>>(spart, ssum);
    out_gemm<<<(NN + 63) / 64, 256, 0, stream>>>(qb_dst, WoT, bo, gamma, beta, gw,
                                                 ssum, d_out);
}